// Round 15
// baseline (69.363 us; speedup 1.0000x reference)
//
#include <hip/hip_runtime.h>

typedef _Float16 f16;
typedef _Float16 f16x4 __attribute__((ext_vector_type(4)));
typedef _Float16 n16x2 __attribute__((ext_vector_type(2)));
typedef float    f32x4 __attribute__((ext_vector_type(4)));

#define LOG2E 1.44269504088896340736f
#define OFF25 36.0673760222824936f   /* 25 * log2(e) */

__device__ __forceinline__ f32x4 MFMA(f16x4 a, f16x4 b, f32x4 c) {
#if defined(__HIP_DEVICE_COMPILE__)
    return __builtin_amdgcn_mfma_f32_16x16x16f16(a, b, c, 0, 0, 0);
#else
    return c;   // host parse stub — never executed
#endif
}

__device__ __forceinline__ float fexp2(float x) {
#if defined(__HIP_DEVICE_COMPILE__)
    return __builtin_amdgcn_exp2f(x);
#else
    return exp2f(x);
#endif
}

__device__ __forceinline__ float flog2(float x) {
#if defined(__HIP_DEVICE_COMPILE__)
    return __builtin_amdgcn_logf(x);     // v_log_f32 = log2
#else
    return log2f(x);
#endif
}

__device__ __forceinline__ f16x4 pk4(float a, float b, float c, float d) {
#if defined(__HIP_DEVICE_COMPILE__)
    n16x2 lo = __builtin_bit_cast(n16x2, __builtin_amdgcn_cvt_pkrtz(a, b));
    n16x2 hi = __builtin_bit_cast(n16x2, __builtin_amdgcn_cvt_pkrtz(c, d));
    f16x4 r; r[0] = lo[0]; r[1] = lo[1]; r[2] = hi[0]; r[3] = hi[1];
    return r;
#else
    f16x4 r; r[0] = (f16)a; r[1] = (f16)b; r[2] = (f16)c; r[3] = (f16)d;
    return r;
#endif
}

// ---------------------------------------------------------------------------
// K1: projections, K-split (unchanged).  F pre-scaled by log2(e); H written
// directly as fragment-order f16.
// ---------------------------------------------------------------------------
__global__ __launch_bounds__(256) void k_proj(const float* __restrict__ x,
        const float* __restrict__ wf, const float* __restrict__ wg,
        const float* __restrict__ wh, f16* __restrict__ F,
        f16* __restrict__ G, f16* __restrict__ Hf) {
    const int lane = threadIdx.x & 63;
    const int wid  = threadIdx.x >> 6;
    const int tile = wid >> 1;
    const int kh   = wid & 1;
    const int g16  = lane >> 4;
    const int c16  = lane & 15;
    const long r0  = ((long)blockIdx.x * 2 + tile) * 16;

    f16x4 bw[3][4];
    const float* Ws[3] = { wf, wg, wh };
    #pragma unroll
    for (int w = 0; w < 3; ++w)
        #pragma unroll
        for (int kk = 0; kk < 4; ++kk) {
            const int kb = (kh * 4 + kk) * 16 + g16 * 4;
            bw[w][kk] = pk4(Ws[w][(kb + 0) * 16 + c16], Ws[w][(kb + 1) * 16 + c16],
                            Ws[w][(kb + 2) * 16 + c16], Ws[w][(kb + 3) * 16 + c16]);
        }

    f32x4 af = {0,0,0,0}, ag = {0,0,0,0}, ah = {0,0,0,0};
    const float* xr = x + (r0 + c16) * 128;
    #pragma unroll
    for (int kk = 0; kk < 4; ++kk) {
        float4 xa = *(const float4*)(xr + (kh * 4 + kk) * 16 + g16 * 4);
        f16x4 a = pk4(xa.x, xa.y, xa.z, xa.w);
        af = MFMA(a, bw[0][kk], af);
        ag = MFMA(a, bw[1][kk], ag);
        ah = MFMA(a, bw[2][kk], ah);
    }

    __shared__ float red[2][64][13];
    if (kh == 1) {
        #pragma unroll
        for (int i = 0; i < 4; ++i) {
            red[tile][lane][i]     = af[i];
            red[tile][lane][4 + i] = ag[i];
            red[tile][lane][8 + i] = ah[i];
        }
    }
    __syncthreads();
    if (kh == 0) {
        #pragma unroll
        for (int i = 0; i < 4; ++i) {
            af[i] += red[tile][lane][i];
            ag[i] += red[tile][lane][4 + i];
            ah[i] += red[tile][lane][8 + i];
        }
        #pragma unroll
        for (int i = 0; i < 4; ++i) {
            const long row = r0 + g16 * 4 + i;
            F[row * 16 + c16] = (f16)(af[i] * LOG2E);   // exp2-domain F
            G[row * 16 + c16] = (f16)ag[i];
        }
        *(f16x4*)(Hf + (r0 >> 4) * 256 + lane * 4) =
            pk4(ah[0], ah[1], ah[2], ah[3]);
    }
}

// ---------------------------------------------------------------------------
// K2: column Z.  1024-thread block = 16 waves; block = 64 m (ga[4]/wave);
// wave tp covers n-sixteenth (256 n, 16 iters), depth-2 prefetch.
// nM2[m] = -log2(z) - OFF25.
// ---------------------------------------------------------------------------
__global__ __launch_bounds__(1024) void k_cs(const f16* __restrict__ F,
        const f16* __restrict__ G, float* __restrict__ nM2) {
    const int lane = threadIdx.x & 63;
    const int tp   = threadIdx.x >> 6;               // 0..15 n-partition
    const int b    = blockIdx.x >> 6;
    const int mb   = (blockIdx.x & 63) * 64;
    const int g16  = lane >> 4, c16 = lane & 15;
    const long bb  = (long)b * 4096;

    f16x4 ga[4];
    #pragma unroll
    for (int j = 0; j < 4; ++j)
        ga[j] = *(const f16x4*)(G + (bb + mb + 16 * j + c16) * 16 + g16 * 4);

    const f16* Fb = F + (bb + tp * 256) * 16;
    float zs[4][4];
    #pragma unroll
    for (int j = 0; j < 4; ++j)
        #pragma unroll
        for (int i = 0; i < 4; ++i) zs[j][i] = 0.f;

    const f32x4 coff = {-OFF25, -OFF25, -OFF25, -OFF25};
    f16x4 fb0 = *(const f16x4*)(Fb + (c16) * 16 + g16 * 4);
    f16x4 fb1 = *(const f16x4*)(Fb + (16 + c16) * 16 + g16 * 4);
    for (int t = 0; t < 16; ++t) {
        f16x4 fbn = *(const f16x4*)(Fb + ((t + 2) * 16 + c16) * 16 + g16 * 4);
        #pragma unroll
        for (int j = 0; j < 4; ++j) {
            f32x4 s = MFMA(ga[j], fb0, coff);        // q = s*log2e - OFF25
            #pragma unroll
            for (int i = 0; i < 4; ++i)
                zs[j][i] += fexp2(s[i]);
        }
        fb0 = fb1; fb1 = fbn;
    }
    #pragma unroll
    for (int d = 8; d >= 1; d >>= 1)
        #pragma unroll
        for (int j = 0; j < 4; ++j)
            #pragma unroll
            for (int i = 0; i < 4; ++i)
                zs[j][i] += __shfl_xor(zs[j][i], d);

    __shared__ float lz[16][64];
    if (c16 == 0) {
        #pragma unroll
        for (int j = 0; j < 4; ++j)
            #pragma unroll
            for (int i = 0; i < 4; ++i)
                lz[tp][16 * j + 4 * g16 + i] = zs[j][i];
    }
    __syncthreads();
    if (threadIdx.x < 64) {
        const int ml = threadIdx.x;
        float z = 0.f;
        #pragma unroll
        for (int p = 0; p < 16; ++p) z += lz[p][ml];
        nM2[bb + mb + ml] = -flog2(z) - OFF25;
    }
}

// ---------------------------------------------------------------------------
// K3: PV + fused output projection.  1024-thread block = 16 waves; block =
// 64 n (fbv[4]); wave tp covers m-sixteenth (256 m, 16 iters), depth-2
// prefetch, linear ha loads.  Hierarchical 16->8->1 LDS reduce in 40 KB;
// epilogue split 16 ways (2 output MFMAs/wave).
// ---------------------------------------------------------------------------
__global__ __launch_bounds__(1024) void k_pv(const f16* __restrict__ F,
        const f16* __restrict__ G, const f16* __restrict__ Hf,
        const float* __restrict__ nM2, const float* __restrict__ wv,
        const float* __restrict__ xin, const float* __restrict__ gamma,
        float* __restrict__ out) {
    const int lane = threadIdx.x & 63;
    const int tp   = threadIdx.x >> 6;               // 0..15 m-partition
    const int b    = blockIdx.x >> 6;
    const int n0   = (blockIdx.x & 63) * 64;
    const int g16  = lane >> 4, c16 = lane & 15;
    const long bb  = (long)b * 4096;

    f16x4 fbv[4];
    #pragma unroll
    for (int j = 0; j < 4; ++j)
        fbv[j] = *(const f16x4*)(F + (bb + n0 + 16 * j + c16) * 16 + g16 * 4);

    // epilogue assignment: wave tp -> n-tile jo (0..3), col-quarter tq (0..3)
    const int jo = tp >> 2, tq = tp & 3;
    const float gm = gamma[0];
    f16x4 wvf[2];
    #pragma unroll
    for (int t = 0; t < 2; ++t) {
        const int c0 = (tq * 2 + t) * 16;
        wvf[t] = pk4(wv[(g16 * 4 + 0) * 128 + c0 + c16] * gm,
                     wv[(g16 * 4 + 1) * 128 + c0 + c16] * gm,
                     wv[(g16 * 4 + 2) * 128 + c0 + c16] * gm,
                     wv[(g16 * 4 + 3) * 128 + c0 + c16] * gm);
    }

    const f16* Gp = G + bb * 16;
    const f16* Hp = Hf + bb * 16 + lane * 4;         // frag-order: +m*16
    const float* Np = nM2 + bb;
    const int mbase = tp * 256;

    f32x4 yT[4] = {{0,0,0,0},{0,0,0,0},{0,0,0,0},{0,0,0,0}};
    f16x4 ga0 = *(const f16x4*)(Gp + (mbase + c16) * 16 + g16 * 4);
    f16x4 ha0 = *(const f16x4*)(Hp + (long)mbase * 16);
    f32x4 nm0 = *(const f32x4*)(Np + mbase + g16 * 4);
    f16x4 ga1 = *(const f16x4*)(Gp + (mbase + 16 + c16) * 16 + g16 * 4);
    f16x4 ha1 = *(const f16x4*)(Hp + (long)(mbase + 16) * 16);
    f32x4 nm1 = *(const f32x4*)(Np + mbase + 16 + g16 * 4);
    for (int t = 0; t < 16; ++t) {
        const int m2 = mbase + t * 16 + 32;   // depth-2; padded: over-read safe
        f16x4 gan = *(const f16x4*)(Gp + (m2 + c16) * 16 + g16 * 4);
        f16x4 han = *(const f16x4*)(Hp + (long)m2 * 16);
        f32x4 nmn = *(const f32x4*)(Np + m2 + g16 * 4);
        #pragma unroll
        for (int j = 0; j < 4; ++j) {
            f32x4 s = MFMA(ga0, fbv[j], nm0);        // q = s' + nm
            f16x4 pb = pk4(fexp2(s[0]), fexp2(s[1]),
                           fexp2(s[2]), fexp2(s[3]));
            yT[j] = MFMA(ha0, pb, yT[j]);
        }
        ga0 = ga1; ha0 = ha1; nm0 = nm1;
        ga1 = gan; ha1 = han; nm1 = nmn;
    }

    // hierarchical reduce: 16 partials -> 8 (LDS) -> 1
    __shared__ float red[8][4][64][5];        // 40 KB, stride-5: conflict-free
    if (tp >= 8) {
        #pragma unroll
        for (int j = 0; j < 4; ++j)
            #pragma unroll
            for (int i = 0; i < 4; ++i) red[tp - 8][j][lane][i] = yT[j][i];
    }
    __syncthreads();
    if (tp < 8) {
        #pragma unroll
        for (int j = 0; j < 4; ++j)
            #pragma unroll
            for (int i = 0; i < 4; ++i)
                red[tp][j][lane][i] += yT[j][i];
    }
    __syncthreads();

    f32x4 ys = {0,0,0,0};
    #pragma unroll
    for (int p = 0; p < 8; ++p)
        #pragma unroll
        for (int i = 0; i < 4; ++i) ys[i] += red[p][jo][lane][i];
    const f16x4 ya = pk4(ys[0], ys[1], ys[2], ys[3]);   // Y A-frag, n-tile jo

    #pragma unroll
    for (int t = 0; t < 2; ++t) {
        const int c0 = (tq * 2 + t) * 16;
        f32x4 zero = {0,0,0,0};
        f32x4 o = MFMA(ya, wvf[t], zero);
        #pragma unroll
        for (int i = 0; i < 4; ++i) {
            const long idx = (bb + n0 + 16 * jo + 4 * g16 + i) * 128 + c0 + c16;
            out[idx] = o[i] + xin[idx];
        }
    }
}

// ---------------------------------------------------------------------------
extern "C" void kernel_launch(void* const* d_in, const int* in_sizes, int n_in,
                              void* d_out, int out_size, void* d_ws, size_t ws_size,
                              hipStream_t stream) {
    const float* x     = (const float*)d_in[0];
    const float* wf    = (const float*)d_in[1];
    const float* wg    = (const float*)d_in[2];
    const float* wh    = (const float*)d_in[3];
    const float* wv    = (const float*)d_in[4];
    const float* gamma = (const float*)d_in[5];
    float* out = (float*)d_out;

    char* p = (char*)d_ws;
    const long BN  = 8L * 4096;
    const long PAD = 8192;
    f16*   F   = (f16*)p;    p += BN * 16 * sizeof(f16) + PAD;
    f16*   G   = (f16*)p;    p += BN * 16 * sizeof(f16) + PAD;
    f16*   Hf  = (f16*)p;    p += BN * 16 * sizeof(f16) + PAD;  // frag-order V
    float* nM2 = (float*)p;  p += BN * sizeof(float)    + PAD;

    k_proj<<<1024, 256,  0, stream>>>(x, wf, wg, wh, F, G, Hf);
    k_cs  <<<512,  1024, 0, stream>>>(F, G, nM2);
    k_pv  <<<512,  1024, 0, stream>>>(F, G, Hf, nM2, wv, x, gamma, out);
}

// Round 16
// 48.738 us; speedup vs baseline: 1.4232x; 1.4232x over previous
//
#include <hip/hip_runtime.h>

typedef _Float16 f16;
typedef _Float16 f16x4 __attribute__((ext_vector_type(4)));
typedef _Float16 n16x2 __attribute__((ext_vector_type(2)));
typedef float    f32x4 __attribute__((ext_vector_type(4)));

#define LOG2E 1.44269504088896340736f
#define OFF25 36.0673760222824936f   /* 25 * log2(e) */

__device__ __forceinline__ f32x4 MFMA(f16x4 a, f16x4 b, f32x4 c) {
#if defined(__HIP_DEVICE_COMPILE__)
    return __builtin_amdgcn_mfma_f32_16x16x16f16(a, b, c, 0, 0, 0);
#else
    return c;   // host parse stub — never executed
#endif
}

__device__ __forceinline__ float fexp2(float x) {
#if defined(__HIP_DEVICE_COMPILE__)
    return __builtin_amdgcn_exp2f(x);
#else
    return exp2f(x);
#endif
}

__device__ __forceinline__ float flog2(float x) {
#if defined(__HIP_DEVICE_COMPILE__)
    return __builtin_amdgcn_logf(x);     // v_log_f32 = log2
#else
    return log2f(x);
#endif
}

__device__ __forceinline__ f16x4 pk4(float a, float b, float c, float d) {
#if defined(__HIP_DEVICE_COMPILE__)
    n16x2 lo = __builtin_bit_cast(n16x2, __builtin_amdgcn_cvt_pkrtz(a, b));
    n16x2 hi = __builtin_bit_cast(n16x2, __builtin_amdgcn_cvt_pkrtz(c, d));
    f16x4 r; r[0] = lo[0]; r[1] = lo[1]; r[2] = hi[0]; r[3] = hi[1];
    return r;
#else
    f16x4 r; r[0] = (f16)a; r[1] = (f16)b; r[2] = (f16)c; r[3] = (f16)d;
    return r;
#endif
}

// ---------------------------------------------------------------------------
// K1: projections, K-split.  F pre-scaled by log2(e); H written directly as
// fragment-order f16.  (round-14, unchanged)
// ---------------------------------------------------------------------------
__global__ __launch_bounds__(256) void k_proj(const float* __restrict__ x,
        const float* __restrict__ wf, const float* __restrict__ wg,
        const float* __restrict__ wh, f16* __restrict__ F,
        f16* __restrict__ G, f16* __restrict__ Hf) {
    const int lane = threadIdx.x & 63;
    const int wid  = threadIdx.x >> 6;
    const int tile = wid >> 1;
    const int kh   = wid & 1;
    const int g16  = lane >> 4;
    const int c16  = lane & 15;
    const long r0  = ((long)blockIdx.x * 2 + tile) * 16;

    f16x4 bw[3][4];
    const float* Ws[3] = { wf, wg, wh };
    #pragma unroll
    for (int w = 0; w < 3; ++w)
        #pragma unroll
        for (int kk = 0; kk < 4; ++kk) {
            const int kb = (kh * 4 + kk) * 16 + g16 * 4;
            bw[w][kk] = pk4(Ws[w][(kb + 0) * 16 + c16], Ws[w][(kb + 1) * 16 + c16],
                            Ws[w][(kb + 2) * 16 + c16], Ws[w][(kb + 3) * 16 + c16]);
        }

    f32x4 af = {0,0,0,0}, ag = {0,0,0,0}, ah = {0,0,0,0};
    const float* xr = x + (r0 + c16) * 128;
    #pragma unroll
    for (int kk = 0; kk < 4; ++kk) {
        float4 xa = *(const float4*)(xr + (kh * 4 + kk) * 16 + g16 * 4);
        f16x4 a = pk4(xa.x, xa.y, xa.z, xa.w);
        af = MFMA(a, bw[0][kk], af);
        ag = MFMA(a, bw[1][kk], ag);
        ah = MFMA(a, bw[2][kk], ah);
    }

    __shared__ float red[2][64][13];
    if (kh == 1) {
        #pragma unroll
        for (int i = 0; i < 4; ++i) {
            red[tile][lane][i]     = af[i];
            red[tile][lane][4 + i] = ag[i];
            red[tile][lane][8 + i] = ah[i];
        }
    }
    __syncthreads();
    if (kh == 0) {
        #pragma unroll
        for (int i = 0; i < 4; ++i) {
            af[i] += red[tile][lane][i];
            ag[i] += red[tile][lane][4 + i];
            ah[i] += red[tile][lane][8 + i];
        }
        #pragma unroll
        for (int i = 0; i < 4; ++i) {
            const long row = r0 + g16 * 4 + i;
            F[row * 16 + c16] = (f16)(af[i] * LOG2E);   // exp2-domain F
            G[row * 16 + c16] = (f16)ag[i];
        }
        *(f16x4*)(Hf + (r0 >> 4) * 256 + lane * 4) =
            pk4(ah[0], ah[1], ah[2], ah[3]);
    }
}

// ---------------------------------------------------------------------------
// K2: column Z (round-14 structure) + XCD-aware block swizzle.
// Grid 512 = 8 batches x 64 m-blocks; hw block n -> (batch n%8, mblock n/8)
// so each XCD's L2 holds exactly one batch's working set (~400 KB).
// ---------------------------------------------------------------------------
__global__ __launch_bounds__(512) void k_cs(const f16* __restrict__ F,
        const f16* __restrict__ G, float* __restrict__ nM2) {
    const int lane = threadIdx.x & 63;
    const int tp   = threadIdx.x >> 6;               // 0..7 n-partition
    const int b    = blockIdx.x & 7;                 // XCD swizzle: batch
    const int mb   = (blockIdx.x >> 3) * 64;         //              m-block
    const int g16  = lane >> 4, c16 = lane & 15;
    const long bb  = (long)b * 4096;

    f16x4 ga[4];
    #pragma unroll
    for (int j = 0; j < 4; ++j)
        ga[j] = *(const f16x4*)(G + (bb + mb + 16 * j + c16) * 16 + g16 * 4);

    const f16* Fb = F + (bb + tp * 512) * 16;
    float zs[4][4];
    #pragma unroll
    for (int j = 0; j < 4; ++j)
        #pragma unroll
        for (int i = 0; i < 4; ++i) zs[j][i] = 0.f;

    const f32x4 coff = {-OFF25, -OFF25, -OFF25, -OFF25};
    f16x4 fb0 = *(const f16x4*)(Fb + (c16) * 16 + g16 * 4);
    f16x4 fb1 = *(const f16x4*)(Fb + (16 + c16) * 16 + g16 * 4);
    f16x4 fb2 = *(const f16x4*)(Fb + (32 + c16) * 16 + g16 * 4);
    for (int t = 0; t < 32; ++t) {
        f16x4 fbn = *(const f16x4*)(Fb + ((t + 3) * 16 + c16) * 16 + g16 * 4);
        #pragma unroll
        for (int j = 0; j < 4; ++j) {
            f32x4 s = MFMA(ga[j], fb0, coff);        // q = s*log2e - OFF25
            #pragma unroll
            for (int i = 0; i < 4; ++i)
                zs[j][i] += fexp2(s[i]);
        }
        fb0 = fb1; fb1 = fb2; fb2 = fbn;
    }
    #pragma unroll
    for (int d = 8; d >= 1; d >>= 1)
        #pragma unroll
        for (int j = 0; j < 4; ++j)
            #pragma unroll
            for (int i = 0; i < 4; ++i)
                zs[j][i] += __shfl_xor(zs[j][i], d);

    __shared__ float lz[8][64];
    if (c16 == 0) {
        #pragma unroll
        for (int j = 0; j < 4; ++j)
            #pragma unroll
            for (int i = 0; i < 4; ++i)
                lz[tp][16 * j + 4 * g16 + i] = zs[j][i];
    }
    __syncthreads();
    if (threadIdx.x < 64) {
        const int ml = threadIdx.x;
        float z = 0.f;
        #pragma unroll
        for (int p = 0; p < 8; ++p) z += lz[p][ml];
        nM2[bb + mb + ml] = -flog2(z) - OFF25;
    }
}

// ---------------------------------------------------------------------------
// K3: PV + fused output projection (round-14 structure) + XCD swizzle.
// ---------------------------------------------------------------------------
__global__ __launch_bounds__(512) void k_pv(const f16* __restrict__ F,
        const f16* __restrict__ G, const f16* __restrict__ Hf,
        const float* __restrict__ nM2, const float* __restrict__ wv,
        const float* __restrict__ xin, const float* __restrict__ gamma,
        float* __restrict__ out) {
    const int lane = threadIdx.x & 63;
    const int tp   = threadIdx.x >> 6;               // 0..7 m-partition
    const int b    = blockIdx.x & 7;                 // XCD swizzle: batch
    const int n0   = (blockIdx.x >> 3) * 64;         //              n-block
    const int g16  = lane >> 4, c16 = lane & 15;
    const long bb  = (long)b * 4096;

    f16x4 fbv[4];
    #pragma unroll
    for (int j = 0; j < 4; ++j)
        fbv[j] = *(const f16x4*)(F + (bb + n0 + 16 * j + c16) * 16 + g16 * 4);

    // epilogue assignment: wave tp -> n-tile jo, col-half th
    const int jo = tp >> 1, th = tp & 1;
    const float gm = gamma[0];
    f16x4 wvf[4];
    #pragma unroll
    for (int t = 0; t < 4; ++t) {
        const int c0 = (4 * th + t) * 16;
        wvf[t] = pk4(wv[(g16 * 4 + 0) * 128 + c0 + c16] * gm,
                     wv[(g16 * 4 + 1) * 128 + c0 + c16] * gm,
                     wv[(g16 * 4 + 2) * 128 + c0 + c16] * gm,
                     wv[(g16 * 4 + 3) * 128 + c0 + c16] * gm);
    }

    const f16* Gp = G + bb * 16;
    const f16* Hp = Hf + bb * 16 + lane * 4;         // frag-order: +m*16
    const float* Np = nM2 + bb;
    const int mbase = tp * 512;

    f32x4 yT[4] = {{0,0,0,0},{0,0,0,0},{0,0,0,0},{0,0,0,0}};
    f16x4 ga0 = *(const f16x4*)(Gp + (mbase + c16) * 16 + g16 * 4);
    f16x4 ha0 = *(const f16x4*)(Hp + (long)mbase * 16);
    f32x4 nm0 = *(const f32x4*)(Np + mbase + g16 * 4);
    f16x4 ga1 = *(const f16x4*)(Gp + (mbase + 16 + c16) * 16 + g16 * 4);
    f16x4 ha1 = *(const f16x4*)(Hp + (long)(mbase + 16) * 16);
    f32x4 nm1 = *(const f32x4*)(Np + mbase + 16 + g16 * 4);
    f16x4 ga2 = *(const f16x4*)(Gp + (mbase + 32 + c16) * 16 + g16 * 4);
    f16x4 ha2 = *(const f16x4*)(Hp + (long)(mbase + 32) * 16);
    f32x4 nm2 = *(const f32x4*)(Np + mbase + 32 + g16 * 4);
    for (int t = 0; t < 32; ++t) {
        const int m3 = mbase + t * 16 + 48;   // depth-3; padded: over-read safe
        f16x4 gan = *(const f16x4*)(Gp + (m3 + c16) * 16 + g16 * 4);
        f16x4 han = *(const f16x4*)(Hp + (long)m3 * 16);
        f32x4 nmn = *(const f32x4*)(Np + m3 + g16 * 4);
        #pragma unroll
        for (int j = 0; j < 4; ++j) {
            f32x4 s = MFMA(ga0, fbv[j], nm0);        // q = s' + nm
            f16x4 pb = pk4(fexp2(s[0]), fexp2(s[1]),
                           fexp2(s[2]), fexp2(s[3]));
            yT[j] = MFMA(ha0, pb, yT[j]);
        }
        ga0 = ga1; ha0 = ha1; nm0 = nm1;
        ga1 = ga2; ha1 = ha2; nm1 = nm2;
        ga2 = gan; ha2 = han; nm2 = nmn;
    }

    // cross-wave reduce: 8 m-partials per n-tile
    __shared__ float red[8][4][64][5];        // 40 KB, stride-5: conflict-free
    #pragma unroll
    for (int j = 0; j < 4; ++j)
        #pragma unroll
        for (int i = 0; i < 4; ++i) red[tp][j][lane][i] = yT[j][i];
    __syncthreads();

    f32x4 ys = {0,0,0,0};
    #pragma unroll
    for (int p = 0; p < 8; ++p)
        #pragma unroll
        for (int i = 0; i < 4; ++i) ys[i] += red[p][jo][lane][i];
    const f16x4 ya = pk4(ys[0], ys[1], ys[2], ys[3]);   // Y A-frag, n-tile jo

    #pragma unroll
    for (int t = 0; t < 4; ++t) {
        const int c0 = (4 * th + t) * 16;
        f32x4 zero = {0,0,0,0};
        f32x4 o = MFMA(ya, wvf[t], zero);
        #pragma unroll
        for (int i = 0; i < 4; ++i) {
            const long idx = (bb + n0 + 16 * jo + 4 * g16 + i) * 128 + c0 + c16;
            out[idx] = o[i] + xin[idx];
        }
    }
}

// ---------------------------------------------------------------------------
extern "C" void kernel_launch(void* const* d_in, const int* in_sizes, int n_in,
                              void* d_out, int out_size, void* d_ws, size_t ws_size,
                              hipStream_t stream) {
    const float* x     = (const float*)d_in[0];
    const float* wf    = (const float*)d_in[1];
    const float* wg    = (const float*)d_in[2];
    const float* wh    = (const float*)d_in[3];
    const float* wv    = (const float*)d_in[4];
    const float* gamma = (const float*)d_in[5];
    float* out = (float*)d_out;

    char* p = (char*)d_ws;
    const long BN  = 8L * 4096;
    const long PAD = 8192;
    f16*   F   = (f16*)p;    p += BN * 16 * sizeof(f16) + PAD;
    f16*   G   = (f16*)p;    p += BN * 16 * sizeof(f16) + PAD;
    f16*   Hf  = (f16*)p;    p += BN * 16 * sizeof(f16) + PAD;  // frag-order V
    float* nM2 = (float*)p;  p += BN * sizeof(float)    + PAD;

    k_proj<<<1024, 256, 0, stream>>>(x, wf, wg, wh, F, G, Hf);
    k_cs  <<<512,  512, 0, stream>>>(F, G, nM2);
    k_pv  <<<512,  512, 0, stream>>>(F, G, Hf, nM2, wv, x, gamma, out);
}